// Round 1
// baseline (427.736 us; speedup 1.0000x reference)
//
#include <hip/hip_runtime.h>
#include <math.h>

// Problem dims (fixed by the harness)
#define NN      16
#define WIDTH   64
#define TT      2048
#define NBINS   2048
#define NROWS   32768      // NN*TT
#define NELEM   2097152    // NN*WIDTH*TT

// ---------------------------------------------------------------------------
// Kernel 0: codebook squared norms
// ---------------------------------------------------------------------------
__global__ __launch_bounds__(256) void cbnorm_k(const float* __restrict__ cb,
                                                float* __restrict__ cbn) {
    int b = blockIdx.x * 256 + threadIdx.x;   // grid 8 * 256 = 2048
    const float4* p = (const float4*)(cb + b * 64);
    float s = 0.f;
#pragma unroll
    for (int i = 0; i < 16; ++i) {
        float4 v = p[i];
        s += v.x * v.x + v.y * v.y + v.z * v.z + v.w * v.w;
    }
    cbn[b] = s;
}

// ---------------------------------------------------------------------------
// Kernel 1: fused dot-product + argmin over 2048 bins.
// Block: 256 threads = 16 tx (bins) x 16 ty (rows). Tile: 64 rows x 128 bins.
// A (x) staged as [k][t] (16 KB); B (codebook) transposed to [k][bin] (33 KB).
// Each thread: 4 rows x 8 bins register tile.
// ---------------------------------------------------------------------------
__global__ __launch_bounds__(256) void argmin_k(
    const float* __restrict__ x, const float* __restrict__ cb,
    const float* __restrict__ cbn, int* __restrict__ g_idx,
    float* __restrict__ fit_part) {
    __shared__ float Alds[64][64];
    __shared__ float Blds[64][132];   // pad 128->132: 16B-aligned b128, 2-way banks
    __shared__ float xnorm_s[64];
    __shared__ float mind2_s[64];

    const int tid = threadIdx.x;
    const int tx = tid & 15;
    const int ty = tid >> 4;

    const int r0 = blockIdx.x * 64;       // global row base
    const int n  = r0 >> 11;              // row = n*2048 + t
    const int t0 = r0 & 2047;
    const float* xp = x + n * (WIDTH * TT) + t0;   // x[n][k][t0..t0+63]

    // Stage A: flat_x[r][k] = x[n][k][t] -> Alds[k][t_local], coalesced along t
#pragma unroll
    for (int it = 0; it < 4; ++it) {
        int f = it * 256 + tid;           // 0..1023 float4s
        int k = f >> 4;
        int tl = (f & 15) << 2;
        float4 v = *(const float4*)(xp + k * TT + tl);
        *(float4*)&Alds[k][tl] = v;
    }
    __syncthreads();

    // per-row ||x||^2 (needed only for mind2 at the end)
    if (tid < 64) {
        float s = 0.f;
#pragma unroll 8
        for (int k = 0; k < 64; ++k) { float a = Alds[k][tid]; s += a * a; }
        xnorm_s[tid] = s;
    }

    float bestv[4] = {3.4e38f, 3.4e38f, 3.4e38f, 3.4e38f};
    int   besti[4] = {0, 0, 0, 0};

    for (int bt = 0; bt < 16; ++bt) {
        const int b0 = bt * 128;
        __syncthreads();   // protect previous tile's Blds reads
        // Stage B with transpose: cb[b][k] -> Blds[k][b]
#pragma unroll
        for (int it = 0; it < 8; ++it) {
            int f = it * 256 + tid;       // 0..2047 float4s
            int b = f >> 4;
            int k0 = (f & 15) << 2;
            float4 v = *(const float4*)(cb + (b0 + b) * 64 + k0);
            Blds[k0 + 0][b] = v.x;
            Blds[k0 + 1][b] = v.y;
            Blds[k0 + 2][b] = v.z;
            Blds[k0 + 3][b] = v.w;
        }
        __syncthreads();

        float cbn_r[8];
        *(float4*)&cbn_r[0] = *(const float4*)(cbn + b0 + (tx << 3));
        *(float4*)&cbn_r[4] = *(const float4*)(cbn + b0 + (tx << 3) + 4);

        float acc[4][8];
#pragma unroll
        for (int i = 0; i < 4; ++i)
#pragma unroll
            for (int j = 0; j < 8; ++j) acc[i][j] = 0.f;

#pragma unroll 8
        for (int k = 0; k < 64; ++k) {
            float4 a = *(const float4*)&Alds[k][ty << 2];
            float bb[8];
            *(float4*)&bb[0] = *(const float4*)&Blds[k][tx << 3];
            *(float4*)&bb[4] = *(const float4*)&Blds[k][(tx << 3) + 4];
#pragma unroll
            for (int j = 0; j < 8; ++j) {
                acc[0][j] = fmaf(a.x, bb[j], acc[0][j]);
                acc[1][j] = fmaf(a.y, bb[j], acc[1][j]);
                acc[2][j] = fmaf(a.z, bb[j], acc[2][j]);
                acc[3][j] = fmaf(a.w, bb[j], acc[3][j]);
            }
        }

        // fold into running min; val = cbnorm[b] - 2*dot  (row-constant ||x||^2 dropped)
#pragma unroll
        for (int j = 0; j < 8; ++j) {
            int b = b0 + (tx << 3) + j;
            float cn = cbn_r[j];
#pragma unroll
            for (int i = 0; i < 4; ++i) {
                float val = fmaf(-2.0f, acc[i][j], cn);
                if (val < bestv[i]) { bestv[i] = val; besti[i] = b; }  // strict < keeps first index
            }
        }
    }

    // reduce across the 16 tx lanes sharing each row group (lowest-index tie-break)
#pragma unroll
    for (int m = 8; m >= 1; m >>= 1) {
#pragma unroll
        for (int i = 0; i < 4; ++i) {
            float ov = __shfl_xor(bestv[i], m, 64);
            int   oi = __shfl_xor(besti[i], m, 64);
            if (ov < bestv[i] || (ov == bestv[i] && oi < besti[i])) {
                bestv[i] = ov; besti[i] = oi;
            }
        }
    }
    if (tx == 0) {
#pragma unroll
        for (int i = 0; i < 4; ++i) {
            int row = (ty << 2) + i;
            g_idx[r0 + row] = besti[i];
            mind2_s[row] = xnorm_s[row] + bestv[i];
        }
    }
    __syncthreads();
    // per-block fit partial: sum over 64 rows of sqrt(max(d2,0)) — wave 0 only
    if (tid < 64) {
        float v = sqrtf(fmaxf(mind2_s[tid], 0.0f));
#pragma unroll
        for (int m = 32; m >= 1; m >>= 1) v += __shfl_xor(v, m, 64);
        if (tid == 0) fit_part[blockIdx.x] = v;
    }
}

// ---------------------------------------------------------------------------
// Kernel 2: gather quantized output (raw-view: out[o]=cb[idx[o>>6]][o&63]),
// mimic reference STE arithmetic out = x + (q - x), and loss partials.
// ---------------------------------------------------------------------------
__global__ __launch_bounds__(256) void gather_k(
    const float* __restrict__ cb, const float* __restrict__ x,
    const int* __restrict__ idx, float* __restrict__ out,
    float* __restrict__ loss_part) {
    int tid = threadIdx.x;
    int o = (blockIdx.x * 256 + tid) << 2;   // grid 2048 -> covers 2,097,152
    int r = o >> 6;
    int c = o & 63;
    int id = idx[r];
    float4 q  = *(const float4*)(cb + (id << 6) + c);
    float4 xv = *(const float4*)(x + o);
    float4 qo;
    qo.x = xv.x + (q.x - xv.x);
    qo.y = xv.y + (q.y - xv.y);
    qo.z = xv.z + (q.z - xv.z);
    qo.w = xv.w + (q.w - xv.w);
    *(float4*)(out + o) = qo;
    float dx = q.x - xv.x, dy = q.y - xv.y, dz = q.z - xv.z, dw = q.w - xv.w;
    float s = dx * dx + dy * dy + dz * dz + dw * dw;
#pragma unroll
    for (int m = 32; m >= 1; m >>= 1) s += __shfl_xor(s, m, 64);
    __shared__ float wsum[4];
    if ((tid & 63) == 0) wsum[tid >> 6] = s;
    __syncthreads();
    if (tid == 0)
        loss_part[blockIdx.x] = wsum[0] + wsum[1] + wsum[2] + wsum[3];
}

// ---------------------------------------------------------------------------
// Kernel 3: deterministic final reduction -> loss, fit scalars
// ---------------------------------------------------------------------------
__global__ __launch_bounds__(256) void final_k(
    const float* __restrict__ loss_part, const float* __restrict__ fit_part,
    float* __restrict__ out) {
    int tid = threadIdx.x;
    float s = 0.f;
    for (int i = tid; i < 2048; i += 256) s += loss_part[i];
    float f = 0.f;
    for (int i = tid; i < 512; i += 256) f += fit_part[i];
#pragma unroll
    for (int m = 32; m >= 1; m >>= 1) {
        s += __shfl_xor(s, m, 64);
        f += __shfl_xor(f, m, 64);
    }
    __shared__ float ss[4], ff[4];
    if ((tid & 63) == 0) { ss[tid >> 6] = s; ff[tid >> 6] = f; }
    __syncthreads();
    if (tid == 0) {
        float loss_sum = ss[0] + ss[1] + ss[2] + ss[3];
        float fit_sum  = ff[0] + ff[1] + ff[2] + ff[3];
        // loss = codebook_loss + 0.25*commit_loss = 1.25 * mean((q-x)^2)
        out[NELEM]     = 1.25f * loss_sum / (float)NELEM;
        out[NELEM + 1] = fit_sum / (float)NROWS;
    }
}

// ---------------------------------------------------------------------------
extern "C" void kernel_launch(void* const* d_in, const int* in_sizes, int n_in,
                              void* d_out, int out_size, void* d_ws, size_t ws_size,
                              hipStream_t stream) {
    const float* x  = (const float*)d_in[0];   // (16,64,2048) fp32
    const float* cb = (const float*)d_in[1];   // (2048,64) fp32
    float* out = (float*)d_out;                // [2097152 quantized][loss][fit]

    // workspace layout (all rewritten every call; no atomics -> deterministic)
    float* cbn       = (float*)d_ws;                               // 2048 f
    int*   idx       = (int*)((char*)d_ws + 8192);                 // 32768 i32
    float* loss_part = (float*)((char*)d_ws + 8192 + 131072);      // 2048 f
    float* fit_part  = (float*)((char*)d_ws + 8192 + 131072 + 8192); // 512 f

    cbnorm_k<<<8, 256, 0, stream>>>(cb, cbn);
    argmin_k<<<512, 256, 0, stream>>>(x, cb, cbn, idx, fit_part);
    gather_k<<<2048, 256, 0, stream>>>(cb, x, idx, out, loss_part);
    final_k<<<1, 256, 0, stream>>>(loss_part, fit_part, out);
}

// Round 2
// 53.083 us; speedup vs baseline: 8.0578x; 8.0578x over previous
//
#include <hip/hip_runtime.h>
#include <math.h>

// Problem dims (fixed by the harness)
#define NN      16
#define WIDTH   64
#define TT      2048
#define NBINS   2048
#define NROWS   32768      // NN*TT
#define NELEM   2097152    // NN*WIDTH*TT

typedef unsigned short u16;
typedef unsigned int   u32;
typedef __attribute__((ext_vector_type(8))) short short8;   // 8 bf16 (4 VGPRs)
typedef __attribute__((ext_vector_type(4))) float f32x4;    // MFMA accumulator

#define MFMA_BF16 __builtin_amdgcn_mfma_f32_16x16x32_bf16

__device__ __forceinline__ u16 f2bf(float f) {            // RNE f32 -> bf16 bits
    u32 u = __float_as_uint(f);
    u32 r = u + 0x7FFFu + ((u >> 16) & 1u);
    return (u16)(r >> 16);
}
__device__ __forceinline__ float bf2f(u16 h) {
    return __uint_as_float(((u32)h) << 16);
}

// ---------------------------------------------------------------------------
// Kernel P0: split codebook into bf16 hi/lo (x = hi + lo, both RNE)
// ---------------------------------------------------------------------------
__global__ __launch_bounds__(256) void cbcvt_k(const float* __restrict__ cb,
                                               u16* __restrict__ hi,
                                               u16* __restrict__ lo) {
    int f = blockIdx.x * 256 + threadIdx.x;   // grid 512 -> 131072 elements
    float v = cb[f];
    u16 h = f2bf(v);
    hi[f] = h;
    lo[f] = f2bf(v - bf2f(h));
}

// ---------------------------------------------------------------------------
// Kernel P1: codebook squared norms (exact fp32, from ORIGINAL cb)
// ---------------------------------------------------------------------------
__global__ __launch_bounds__(256) void cbnorm_k(const float* __restrict__ cb,
                                                float* __restrict__ cbn) {
    int b = blockIdx.x * 256 + threadIdx.x;   // grid 8
    const float4* p = (const float4*)(cb + b * 64);
    float s = 0.f;
#pragma unroll
    for (int i = 0; i < 16; ++i) {
        float4 v = p[i];
        s += v.x * v.x + v.y * v.y + v.z * v.z + v.w * v.w;
    }
    cbn[b] = s;
}

// ---------------------------------------------------------------------------
// Kernel 1: MFMA argmin. Block = 64 rows x all 2048 bins (16 tiles of 128).
// 4 waves; wave w owns bins w*32..w*32+31 of each tile, all 64 rows.
// discriminant d = cbn[b] - 2*dot(x_r, cb_b); dot via 3-term bf16 split MFMA.
// All LDS access patterns are <=2-way bank conflicted (free).
// ---------------------------------------------------------------------------
__global__ __launch_bounds__(256, 2) void argmin_k(
    const float* __restrict__ x, const u16* __restrict__ cbhi,
    const u16* __restrict__ cblo, const float* __restrict__ cbn,
    int* __restrict__ g_idx, float* __restrict__ fit_part) {
    // A: [t][k] bf16, 64x64, XOR-swizzled: elem = t*64 + (k ^ ((t&7)<<3))
    __shared__ __align__(16) u16 Ah[4096], Al[4096];
    // B: [bin][k] bf16, 128 x stride 72 (144B rows -> 2-way banks)
    __shared__ __align__(16) u16 Bh[9216], Bl[9216];
    __shared__ float xnp[4][64];
    __shared__ float xnorm_s[64];
    __shared__ float bv_s[4][64];
    __shared__ int   bi_s[4][64];

    const int tid  = threadIdx.x;
    const int lane = tid & 63;
    const int w    = tid >> 6;      // wave 0..3
    const int col  = lane & 15;     // MFMA n / m row-index for frags
    const int kseg = lane >> 4;     // 0..3 (k-segment of fragments)

    const int r0 = blockIdx.x * 64;   // rows r0..r0+63; row = n*2048 + t
    const int n  = r0 >> 11;
    const int t0 = r0 & 2047;

    // ---- Stage A (fp32 x -> hi/lo bf16, transposed to [t][k]) + xnorm ----
    {
        const int t  = tid & 63;
        const int kb = tid >> 6;     // 0..3
        const float* xp = x + (size_t)n * (WIDTH * TT) + t0 + t;
        const int sw = (t & 7) << 3;
        float xs = 0.f;
#pragma unroll
        for (int it = 0; it < 16; ++it) {
            int k = it * 4 + kb;
            float v = xp[(size_t)k * TT];   // wave reads 64 consecutive t: coalesced
            xs += v * v;
            u16 h = f2bf(v);
            u16 l = f2bf(v - bf2f(h));
            int a = t * 64 + (k ^ sw);
            Ah[a] = h; Al[a] = l;
        }
        xnp[kb][t] = xs;
    }
    __syncthreads();
    if (tid < 64)
        xnorm_s[tid] = xnp[0][tid] + xnp[1][tid] + xnp[2][tid] + xnp[3][tid];

    // ---- A fragments, held in registers across all bin tiles ----
    // frag element i of lane: A[row = rs*16 + col][k = kc*32 + kseg*8 + i]
    short8 afh[4][2], afl[4][2];
#pragma unroll
    for (int rs = 0; rs < 4; ++rs) {
        const int rt = rs * 16 + col;
        const int sw = (rt & 7) << 3;
#pragma unroll
        for (int kc = 0; kc < 2; ++kc) {
            int k0 = kc * 32 + kseg * 8;
            int a = rt * 64 + (k0 ^ sw);   // k0 mult of 8 -> XOR keeps 8 contiguous
            afh[rs][kc] = *(const short8*)&Ah[a];
            afl[rs][kc] = *(const short8*)&Al[a];
        }
    }

    // ---- B staging: register prefetch (tile 0) ----
    const int sbin = tid >> 3;   // 0..31
    const int schk = tid & 7;    // 0..7
    short8 pbh[4], pbl[4];
#pragma unroll
    for (int j = 0; j < 4; ++j) {
        size_t g = (size_t)(sbin + 32 * j) * 64 + schk * 8;
        pbh[j] = *(const short8*)&cbhi[g];
        pbl[j] = *(const short8*)&cblo[g];
    }

    float bestv[16];
    int   besti[16];
#pragma unroll
    for (int i = 0; i < 16; ++i) { bestv[i] = 3.4e38f; besti[i] = 0; }

    for (int tile = 0; tile < 16; ++tile) {
        __syncthreads();   // previous tile's B reads done
#pragma unroll
        for (int j = 0; j < 4; ++j) {
            int a = (sbin + 32 * j) * 72 + schk * 8;
            *(short8*)&Bh[a] = pbh[j];
            *(short8*)&Bl[a] = pbl[j];
        }
        if (tile < 15) {
            const size_t gb = (size_t)(tile + 1) * 128 * 64;
#pragma unroll
            for (int j = 0; j < 4; ++j) {
                size_t g = gb + (size_t)(sbin + 32 * j) * 64 + schk * 8;
                pbh[j] = *(const short8*)&cbhi[g];
                pbl[j] = *(const short8*)&cblo[g];
            }
        }
        const int gb0 = tile * 128 + w * 32 + col;   // this lane's s=0 bin
        const float cb0 = cbn[gb0];
        const float cb1 = cbn[gb0 + 16];
        __syncthreads();   // B tile ready

        // B fragments: B[k][n] = cb[bin0+n][k], n = col, k = kc*32+kseg*8+i
        short8 bfh[2][2], bfl[2][2];
#pragma unroll
        for (int s = 0; s < 2; ++s) {
            const int bl_ = w * 32 + s * 16 + col;
#pragma unroll
            for (int kc = 0; kc < 2; ++kc) {
                int a = bl_ * 72 + kc * 32 + kseg * 8;
                bfh[s][kc] = *(const short8*)&Bh[a];
                bfl[s][kc] = *(const short8*)&Bl[a];
            }
        }

        // 3-term split MFMA: dot = hi*hi + hi*lo + lo*hi (fp32 accumulate)
        f32x4 acc[4][2];
#pragma unroll
        for (int rs = 0; rs < 4; ++rs)
#pragma unroll
            for (int s = 0; s < 2; ++s) {
                f32x4 a = {0.f, 0.f, 0.f, 0.f};
#pragma unroll
                for (int kc = 0; kc < 2; ++kc) {
                    a = MFMA_BF16(afh[rs][kc], bfh[s][kc], a, 0, 0, 0);
                    a = MFMA_BF16(afh[rs][kc], bfl[s][kc], a, 0, 0, 0);
                    a = MFMA_BF16(afl[rs][kc], bfh[s][kc], a, 0, 0, 0);
                }
                acc[rs][s] = a;
            }

        // fold: C/D layout col=lane&15, row=(lane>>4)*4+reg (HW-verified)
#pragma unroll
        for (int rs = 0; rs < 4; ++rs)
#pragma unroll
            for (int s = 0; s < 2; ++s) {
                const float cbv = s ? cb1 : cb0;
                const int bin = gb0 + s * 16;
#pragma unroll
                for (int jj = 0; jj < 4; ++jj) {
                    float d = fmaf(-2.f, acc[rs][s][jj], cbv);
                    int li = rs * 4 + jj;
                    if (d < bestv[li]) { bestv[li] = d; besti[li] = bin; }
                }
            }
    }

    // ---- reduce across the 16 col-lanes sharing each row ----
#pragma unroll
    for (int m = 1; m <= 8; m <<= 1) {
#pragma unroll
        for (int i = 0; i < 16; ++i) {
            float ov = __shfl_xor(bestv[i], m, 64);
            int   oi = __shfl_xor(besti[i], m, 64);
            if (ov < bestv[i] || (ov == bestv[i] && oi < besti[i])) {
                bestv[i] = ov; besti[i] = oi;
            }
        }
    }
    if (col == 0) {
#pragma unroll
        for (int rs = 0; rs < 4; ++rs)
#pragma unroll
            for (int jj = 0; jj < 4; ++jj) {
                int rt = rs * 16 + kseg * 4 + jj;
                bv_s[w][rt] = bestv[rs * 4 + jj];
                bi_s[w][rt] = besti[rs * 4 + jj];
            }
    }
    __syncthreads();
    // ---- cross-wave merge (bins interleave across waves: compare by index) ----
    if (tid < 64) {
        float bv = bv_s[0][tid]; int bi = bi_s[0][tid];
#pragma unroll
        for (int ww = 1; ww < 4; ++ww) {
            float v = bv_s[ww][tid]; int ii = bi_s[ww][tid];
            if (v < bv || (v == bv && ii < bi)) { bv = v; bi = ii; }
        }
        g_idx[r0 + tid] = bi;
        float d2 = xnorm_s[tid] + bv;
        float md = sqrtf(fmaxf(d2, 0.f));
#pragma unroll
        for (int m = 32; m >= 1; m >>= 1) md += __shfl_xor(md, m, 64);
        if (tid == 0) fit_part[blockIdx.x] = md;
    }
}

// ---------------------------------------------------------------------------
// Kernel 2: gather quantized output (raw view: out[o]=cb[idx[o>>6]][o&63]),
// mimic reference STE arithmetic out = x + (q - x), loss partials.
// ---------------------------------------------------------------------------
__global__ __launch_bounds__(256) void gather_k(
    const float* __restrict__ cb, const float* __restrict__ x,
    const int* __restrict__ idx, float* __restrict__ out,
    float* __restrict__ loss_part) {
    int tid = threadIdx.x;
    int o = (blockIdx.x * 256 + tid) << 2;   // grid 2048
    int r = o >> 6;
    int c = o & 63;
    int id = idx[r];
    float4 q  = *(const float4*)(cb + (id << 6) + c);
    float4 xv = *(const float4*)(x + o);
    float4 qo;
    qo.x = xv.x + (q.x - xv.x);
    qo.y = xv.y + (q.y - xv.y);
    qo.z = xv.z + (q.z - xv.z);
    qo.w = xv.w + (q.w - xv.w);
    *(float4*)(out + o) = qo;
    float dx = q.x - xv.x, dy = q.y - xv.y, dz = q.z - xv.z, dw = q.w - xv.w;
    float s = dx * dx + dy * dy + dz * dz + dw * dw;
#pragma unroll
    for (int m = 32; m >= 1; m >>= 1) s += __shfl_xor(s, m, 64);
    __shared__ float wsum[4];
    if ((tid & 63) == 0) wsum[tid >> 6] = s;
    __syncthreads();
    if (tid == 0)
        loss_part[blockIdx.x] = wsum[0] + wsum[1] + wsum[2] + wsum[3];
}

// ---------------------------------------------------------------------------
// Kernel 3: deterministic final reduction -> loss, fit scalars
// ---------------------------------------------------------------------------
__global__ __launch_bounds__(256) void final_k(
    const float* __restrict__ loss_part, const float* __restrict__ fit_part,
    float* __restrict__ out) {
    int tid = threadIdx.x;
    float s = 0.f;
    for (int i = tid; i < 2048; i += 256) s += loss_part[i];
    float f = 0.f;
    for (int i = tid; i < 512; i += 256) f += fit_part[i];
#pragma unroll
    for (int m = 32; m >= 1; m >>= 1) {
        s += __shfl_xor(s, m, 64);
        f += __shfl_xor(f, m, 64);
    }
    __shared__ float ss[4], ff[4];
    if ((tid & 63) == 0) { ss[tid >> 6] = s; ff[tid >> 6] = f; }
    __syncthreads();
    if (tid == 0) {
        float loss_sum = ss[0] + ss[1] + ss[2] + ss[3];
        float fit_sum  = ff[0] + ff[1] + ff[2] + ff[3];
        // loss = codebook_loss + 0.25*commit_loss = 1.25 * mean((q-x)^2)
        out[NELEM]     = 1.25f * loss_sum / (float)NELEM;
        out[NELEM + 1] = fit_sum / (float)NROWS;
    }
}

// ---------------------------------------------------------------------------
extern "C" void kernel_launch(void* const* d_in, const int* in_sizes, int n_in,
                              void* d_out, int out_size, void* d_ws, size_t ws_size,
                              hipStream_t stream) {
    const float* x  = (const float*)d_in[0];   // (16,64,2048) fp32
    const float* cb = (const float*)d_in[1];   // (2048,64) fp32
    float* out = (float*)d_out;                // [2097152 quantized][loss][fit]

    // workspace layout (all rewritten every call; no atomics -> deterministic)
    char* ws = (char*)d_ws;
    float* cbn       = (float*)(ws);                  // 8 KB
    int*   idx       = (int*)  (ws + 8192);           // 128 KB
    float* loss_part = (float*)(ws + 139264);         // 8 KB
    float* fit_part  = (float*)(ws + 147456);         // 2 KB
    u16*   cbhi      = (u16*)  (ws + 149504);         // 256 KB
    u16*   cblo      = (u16*)  (ws + 411648);         // 256 KB (total ~658 KB)

    cbcvt_k <<<512, 256, 0, stream>>>(cb, cbhi, cblo);
    cbnorm_k<<<8,   256, 0, stream>>>(cb, cbn);
    argmin_k<<<512, 256, 0, stream>>>(x, cbhi, cblo, cbn, idx, fit_part);
    gather_k<<<2048,256, 0, stream>>>(cb, x, idx, out, loss_part);
    final_k <<<1,   256, 0, stream>>>(loss_part, fit_part, out);
}

// Round 3
// 38.845 us; speedup vs baseline: 11.0114x; 1.3665x over previous
//
#include <hip/hip_runtime.h>
#include <math.h>

// Problem dims (fixed)
#define NN      16
#define WIDTH   64
#define TT      2048
#define NBINS   2048
#define NROWS   32768      // NN*TT
#define NELEM   2097152    // NN*WIDTH*TT

typedef unsigned short u16;
typedef unsigned int   u32;
typedef __attribute__((ext_vector_type(8))) short short8;   // 8 bf16 (4 VGPRs)
typedef __attribute__((ext_vector_type(4))) float f32x4;

#define MFMA_BF16 __builtin_amdgcn_mfma_f32_16x16x32_bf16

__device__ __forceinline__ u16 f2bf(float f) {            // RNE f32 -> bf16 bits
    u32 u = __float_as_uint(f);
    u32 r = u + 0x7FFFu + ((u >> 16) & 1u);
    return (u16)(r >> 16);
}

// ---------------------------------------------------------------------------
// Prep: codebook -> bf16 (RNE) + exact fp32 squared norms. One thread per bin.
// ---------------------------------------------------------------------------
__global__ __launch_bounds__(256) void cbprep_k(const float* __restrict__ cb,
                                                u16* __restrict__ cbhi,
                                                float* __restrict__ cbn) {
    int b = blockIdx.x * 256 + threadIdx.x;   // grid 8 -> 2048 bins
    const float4* p = (const float4*)(cb + (size_t)b * 64);
    float s = 0.f;
#pragma unroll
    for (int g = 0; g < 8; ++g) {
        float4 v0 = p[g * 2], v1 = p[g * 2 + 1];
        s += v0.x * v0.x + v0.y * v0.y + v0.z * v0.z + v0.w * v0.w;
        s += v1.x * v1.x + v1.y * v1.y + v1.z * v1.z + v1.w * v1.w;
        short8 h = { (short)f2bf(v0.x), (short)f2bf(v0.y), (short)f2bf(v0.z),
                     (short)f2bf(v0.w), (short)f2bf(v1.x), (short)f2bf(v1.y),
                     (short)f2bf(v1.z), (short)f2bf(v1.w) };
        *(short8*)&cbhi[(size_t)b * 64 + g * 8] = h;
    }
    cbn[b] = s;
}

// ---------------------------------------------------------------------------
// Main: per block = 128 rows x all 2048 bins. 512 threads = 8 waves.
// wave wv: rg = wv>>2 (row half), bg = wv&3 (32-bin slice of each 128-bin tile).
// B fragments streamed DIRECTLY from global (L2-resident), register
// double-buffered -> no barriers in the 16-tile loop.
// discriminant d = cbn[b] - 2*dot_bf16(x_r, cb_b); exact tie-break by index.
// Epilogue: fused raw-view gather + STE write + loss/fit partials.
// ---------------------------------------------------------------------------
__global__ __launch_bounds__(512, 2) void vq_main_k(
    const float* __restrict__ x, const u16* __restrict__ cbhi,
    const float* __restrict__ cbn, const float* __restrict__ cb,
    float* __restrict__ out, float* __restrict__ loss_part,
    float* __restrict__ fit_part) {
    // A: [t][k] bf16, 128x64, XOR-swizzled: elem = t*64 + (k ^ ((t&7)<<3))
    __shared__ __align__(16) u16 Ah[128 * 64];
    __shared__ float xnp[4][128];
    __shared__ float xnorm_s[128];
    __shared__ float bv_s[4][128];
    __shared__ int   bi_s[4][128];
    __shared__ int   bi_m[128];
    __shared__ float red_f[2];
    __shared__ float red_l[8];

    const int tid  = threadIdx.x;
    const int lane = tid & 63;
    const int wv   = tid >> 6;      // 0..7
    const int rg   = wv >> 2;       // row group (0: rows 0..63, 1: 64..127)
    const int bg   = wv & 3;        // bin sub-slice
    const int col  = lane & 15;
    const int kseg = lane >> 4;     // 0..3

    const int r0 = blockIdx.x * 128;   // rows r0..r0+127; row = n*2048 + t
    const int n  = r0 >> 11;
    const int t0 = r0 & 2047;

    // ---- B prefetch, tile 0 (issued before A staging to hide latency) ----
    short8 bh[2][2][2];     // [buf][s][kc]
    float  cbnv[2][2];
    {
        const int binb = bg * 32 + col;
#pragma unroll
        for (int s = 0; s < 2; ++s) {
            cbnv[0][s] = cbn[binb + s * 16];
#pragma unroll
            for (int kc = 0; kc < 2; ++kc)
                bh[0][s][kc] = *(const short8*)
                    &cbhi[(size_t)(binb + s * 16) * 64 + kc * 32 + kseg * 8];
        }
    }

    // ---- Stage A: x fp32 -> bf16, transposed to [t][k]; exact xnorm ----
    {
        const int t  = tid & 127;
        const int kb = tid >> 7;     // 0..3
        const float* xp = x + (size_t)n * (WIDTH * TT) + t0 + t;
        const int sw = (t & 7) << 3;
        float xs = 0.f;
#pragma unroll
        for (int it = 0; it < 8; ++it) {
            int k2 = kb * 16 + it * 2;
            float v0 = xp[(size_t)k2 * TT];
            float v1 = xp[(size_t)(k2 + 1) * TT];
            xs += v0 * v0 + v1 * v1;
            u32 pack = (u32)f2bf(v0) | ((u32)f2bf(v1) << 16);
            *(u32*)&Ah[t * 64 + (k2 ^ sw)] = pack;   // k2 even, XOR keeps pair
        }
        xnp[kb][t] = xs;
    }
    __syncthreads();
    if (tid < 128)
        xnorm_s[tid] = xnp[0][tid] + xnp[1][tid] + xnp[2][tid] + xnp[3][tid];

    // ---- A fragments in registers (held across all 16 tiles) ----
    short8 afh[4][2];
#pragma unroll
    for (int rs = 0; rs < 4; ++rs) {
        const int rt = rg * 64 + rs * 16 + col;
        const int sw = (rt & 7) << 3;
#pragma unroll
        for (int kc = 0; kc < 2; ++kc)
            afh[rs][kc] = *(const short8*)&Ah[rt * 64 + ((kc * 32 + kseg * 8) ^ sw)];
    }

    float bestv[16]; int bestb[16];
#pragma unroll
    for (int i = 0; i < 16; ++i) { bestv[i] = 3.4e38f; bestb[i] = 0; }

    // ---- 16-tile main loop: no barriers, register-dbuf global B stream ----
#pragma unroll 2
    for (int tile = 0; tile < 16; ++tile) {
        const int buf = tile & 1, nbuf = buf ^ 1;
        const int tn = (tile + 1) & 15;        // wraps: harmless extra prefetch
        {
            const int binb = tn * 128 + bg * 32 + col;
#pragma unroll
            for (int s = 0; s < 2; ++s) {
                cbnv[nbuf][s] = cbn[binb + s * 16];
#pragma unroll
                for (int kc = 0; kc < 2; ++kc)
                    bh[nbuf][s][kc] = *(const short8*)
                        &cbhi[(size_t)(binb + s * 16) * 64 + kc * 32 + kseg * 8];
            }
        }
        f32x4 acc[4][2];
#pragma unroll
        for (int rs = 0; rs < 4; ++rs)
#pragma unroll
            for (int s = 0; s < 2; ++s) {
                f32x4 a = {0.f, 0.f, 0.f, 0.f};
                a = MFMA_BF16(afh[rs][0], bh[buf][s][0], a, 0, 0, 0);
                a = MFMA_BF16(afh[rs][1], bh[buf][s][1], a, 0, 0, 0);
                acc[rs][s] = a;
            }
        const int bin0 = tile * 128 + bg * 32 + col;
#pragma unroll
        for (int rs = 0; rs < 4; ++rs)
#pragma unroll
            for (int s = 0; s < 2; ++s) {
                const float cv = cbnv[buf][s];
                const int bb = bin0 + s * 16;
#pragma unroll
                for (int jj = 0; jj < 4; ++jj) {
                    float d = fmaf(-2.f, acc[rs][s][jj], cv);
                    int li = rs * 4 + jj;
                    bool c = d < bestv[li];            // strict: first index wins
                    bestv[li] = c ? d : bestv[li];
                    bestb[li] = c ? bb : bestb[li];
                }
            }
    }

    // ---- reduce across 16 col-lanes (lowest-index tie-break) ----
#pragma unroll
    for (int m = 1; m <= 8; m <<= 1) {
#pragma unroll
        for (int i = 0; i < 16; ++i) {
            float ov = __shfl_xor(bestv[i], m, 64);
            int   oi = __shfl_xor(bestb[i], m, 64);
            bool c = (ov < bestv[i]) || (ov == bestv[i] && oi < bestb[i]);
            bestv[i] = c ? ov : bestv[i];
            bestb[i] = c ? oi : bestb[i];
        }
    }
    if (col == 0) {
#pragma unroll
        for (int rs = 0; rs < 4; ++rs)
#pragma unroll
            for (int jj = 0; jj < 4; ++jj) {
                int row = rg * 64 + rs * 16 + kseg * 4 + jj;
                bv_s[bg][row] = bestv[rs * 4 + jj];
                bi_s[bg][row] = bestb[rs * 4 + jj];
            }
    }
    __syncthreads();

    // ---- cross-bin-group merge + fit partial ----
    if (tid < 128) {
        float bv = bv_s[0][tid]; int bi = bi_s[0][tid];
#pragma unroll
        for (int g = 1; g < 4; ++g) {
            float v = bv_s[g][tid]; int ii = bi_s[g][tid];
            bool c = (v < bv) || (v == bv && ii < bi);
            bv = c ? v : bv; bi = c ? ii : bi;
        }
        bi_m[tid] = bi;
        float fv = sqrtf(fmaxf(xnorm_s[tid] + bv, 0.f));
#pragma unroll
        for (int m = 32; m >= 1; m >>= 1) fv += __shfl_xor(fv, m, 64);
        if (lane == 0) red_f[wv] = fv;
    }
    __syncthreads();
    if (tid == 0) fit_part[blockIdx.x] = red_f[0] + red_f[1];

    // ---- fused epilogue: raw-view gather + STE write + loss partial ----
    // block owns flat out range [r0*64, r0*64 + 8192)
    const size_t ob = (size_t)r0 * 64 + (size_t)tid * 16;
    const int rl = tid >> 2;                 // local row 0..127
    const int id = bi_m[rl];
    const float* qrow = cb + (size_t)id * 64 + (tid & 3) * 16;
    float ls = 0.f;
#pragma unroll
    for (int j = 0; j < 4; ++j) {
        float4 q  = *(const float4*)(qrow + j * 4);
        float4 xv = *(const float4*)(x + ob + j * 4);
        float4 qo;
        qo.x = xv.x + (q.x - xv.x);
        qo.y = xv.y + (q.y - xv.y);
        qo.z = xv.z + (q.z - xv.z);
        qo.w = xv.w + (q.w - xv.w);
        *(float4*)(out + ob + j * 4) = qo;
        float dx = q.x - xv.x, dy = q.y - xv.y, dz = q.z - xv.z, dw = q.w - xv.w;
        ls += dx * dx + dy * dy + dz * dz + dw * dw;
    }
#pragma unroll
    for (int m = 32; m >= 1; m >>= 1) ls += __shfl_xor(ls, m, 64);
    if (lane == 0) red_l[wv] = ls;
    __syncthreads();
    if (tid == 0) {
        float t = 0.f;
#pragma unroll
        for (int i = 0; i < 8; ++i) t += red_l[i];
        loss_part[blockIdx.x] = t;
    }
}

// ---------------------------------------------------------------------------
// Final deterministic reduction -> loss, fit scalars
// ---------------------------------------------------------------------------
__global__ __launch_bounds__(256) void final_k(
    const float* __restrict__ loss_part, const float* __restrict__ fit_part,
    float* __restrict__ out) {
    int tid = threadIdx.x;
    float s = loss_part[tid];
    float f = fit_part[tid];
#pragma unroll
    for (int m = 32; m >= 1; m >>= 1) {
        s += __shfl_xor(s, m, 64);
        f += __shfl_xor(f, m, 64);
    }
    __shared__ float ss[4], ff[4];
    if ((tid & 63) == 0) { ss[tid >> 6] = s; ff[tid >> 6] = f; }
    __syncthreads();
    if (tid == 0) {
        float loss_sum = ss[0] + ss[1] + ss[2] + ss[3];
        float fit_sum  = ff[0] + ff[1] + ff[2] + ff[3];
        // loss = codebook_loss + 0.25*commit_loss = 1.25 * mean((q-x)^2)
        out[NELEM]     = 1.25f * loss_sum / (float)NELEM;
        out[NELEM + 1] = fit_sum / (float)NROWS;
    }
}

// ---------------------------------------------------------------------------
extern "C" void kernel_launch(void* const* d_in, const int* in_sizes, int n_in,
                              void* d_out, int out_size, void* d_ws, size_t ws_size,
                              hipStream_t stream) {
    const float* x  = (const float*)d_in[0];   // (16,64,2048) fp32
    const float* cb = (const float*)d_in[1];   // (2048,64) fp32
    float* out = (float*)d_out;                // [2097152 quantized][loss][fit]

    char* ws = (char*)d_ws;
    float* cbn       = (float*)(ws);            // 8 KB
    u16*   cbhi      = (u16*)  (ws + 8192);     // 256 KB
    float* loss_part = (float*)(ws + 270336);   // 1 KB (256 f)
    float* fit_part  = (float*)(ws + 271360);   // 1 KB (256 f)

    cbprep_k<<<8,   256, 0, stream>>>(cb, cbhi, cbn);
    vq_main_k<<<256, 512, 0, stream>>>(x, cbhi, cbn, cb, out, loss_part, fit_part);
    final_k <<<1,   256, 0, stream>>>(loss_part, fit_part, out);
}

// Round 4
// 25.320 us; speedup vs baseline: 16.8935x; 1.5342x over previous
//
#include <hip/hip_runtime.h>
#include <math.h>

// Problem dims (fixed)
#define NN      16
#define WIDTH   64
#define TT      2048
#define NBINS   2048
#define NROWS   32768      // NN*TT
#define NELEM   2097152    // NN*WIDTH*TT

typedef unsigned short u16;
typedef unsigned int   u32;
typedef __attribute__((ext_vector_type(8))) short short8;   // 8 bf16 (4 VGPRs)
typedef __attribute__((ext_vector_type(4))) float f32x4;

#define MFMA_BF16 __builtin_amdgcn_mfma_f32_16x16x32_bf16
#define KEYMASK   0xFFFFF800u
#define DBIAS     0.125f

__device__ __forceinline__ u16 f2bf(float f) {            // RNE f32 -> bf16 bits
    u32 u = __float_as_uint(f);
    u32 r = u + 0x7FFFu + ((u >> 16) & 1u);
    return (u16)(r >> 16);
}

// ---------------------------------------------------------------------------
// Prep: codebook -> bf16 in MFMA-tiled layout cbT + biased norms cbnC.
// cbT chunk layout: [bin16][kc][kseg][col][8elem] ; bin=bin16*16+col,
// k = kc*32 + kseg*8 + i  -> a wave's B-fragment load is 1KB contiguous.
// ---------------------------------------------------------------------------
__global__ __launch_bounds__(256) void cbprep_k(const float* __restrict__ cb,
                                                u16* __restrict__ cbT,
                                                float* __restrict__ cbnC) {
    int b = blockIdx.x * 256 + threadIdx.x;   // grid 8 -> 2048 bins
    const float4* p = (const float4*)(cb + (size_t)b * 64);
    float s = 0.f;
    const int base = (b >> 4) * 1024 + (b & 15) * 8;
#pragma unroll
    for (int o = 0; o < 8; ++o) {             // k-octet: kc=o>>2, kseg=o&3
        float4 v0 = p[o * 2], v1 = p[o * 2 + 1];
        s += v0.x * v0.x + v0.y * v0.y + v0.z * v0.z + v0.w * v0.w;
        s += v1.x * v1.x + v1.y * v1.y + v1.z * v1.z + v1.w * v1.w;
        short8 h = { (short)f2bf(v0.x), (short)f2bf(v0.y), (short)f2bf(v0.z),
                     (short)f2bf(v0.w), (short)f2bf(v1.x), (short)f2bf(v1.y),
                     (short)f2bf(v1.z), (short)f2bf(v1.w) };
        *(short8*)&cbT[base + (o >> 2) * 512 + (o & 3) * 128] = h;
    }
    cbnC[b] = s + DBIAS;
}

// ---------------------------------------------------------------------------
// Main: block = 64 rows x all 2048 bins. 256 threads = 4 waves, wave = bin
// slice bg (32 bins of each 128-bin tile), all 64 rows (4 MFMA row-tiles).
// B streamed from L2 via named register double-buffer (no runtime indexing,
// no barriers in the 16-tile loop). Argmin via sortable u32 keys:
//   d = cbnC[b] - 2*dot  (>0 by construction), key = (bits(d)&~0x7FF)|bin.
// Epilogue: fused raw-view gather + STE write + loss/fit partials.
// ---------------------------------------------------------------------------
__global__ __launch_bounds__(256, 2) void vq_main_k(
    const float* __restrict__ x, const u16* __restrict__ cbT,
    const float* __restrict__ cbnC, const float* __restrict__ cb,
    float* __restrict__ out, float* __restrict__ loss_part,
    float* __restrict__ fit_part) {
    // A: [t][k] bf16, 64x64, XOR-swizzled: elem = t*64 + (k ^ ((t&7)<<3))
    __shared__ __align__(16) u16 Ah[64 * 64];
    __shared__ float xnp[4][64];
    __shared__ float xnorm_s[64];
    __shared__ u32   kq_s[4][64];
    __shared__ int   bi_m[64];
    __shared__ float red_l[4];

    const int tid  = threadIdx.x;
    const int lane = tid & 63;
    const int bg   = tid >> 6;      // wave 0..3 = bin sub-slice
    const int col  = lane & 15;
    const int kseg = lane >> 4;     // 0..3

    const int r0 = blockIdx.x * 64;   // rows r0..r0+63; row = n*2048 + t
    const int n  = r0 >> 11;
    const int t0 = r0 & 2047;

    // ---- Stage A: x fp32 -> bf16 [t][k] swizzled; exact fp32 xnorm ----
    {
        const int t  = tid & 63;
        const int kb = tid >> 6;     // 0..3
        const float* xp = x + (size_t)n * (WIDTH * TT) + t0 + t;
        const int sw = (t & 7) << 3;
        float xs = 0.f;
#pragma unroll
        for (int it = 0; it < 8; ++it) {
            int k2 = kb * 16 + it * 2;
            float v0 = xp[(size_t)k2 * TT];
            float v1 = xp[(size_t)(k2 + 1) * TT];
            xs += v0 * v0 + v1 * v1;
            u32 pack = (u32)f2bf(v0) | ((u32)f2bf(v1) << 16);
            *(u32*)&Ah[t * 64 + (k2 ^ sw)] = pack;   // k2 even -> pair intact
        }
        xnp[kb][t] = xs;
    }
    __syncthreads();
    if (tid < 64)
        xnorm_s[tid] = xnp[0][tid] + xnp[1][tid] + xnp[2][tid] + xnp[3][tid];

    // ---- A fragments in registers (held across all 16 tiles) ----
    short8 afh[4][2];
#pragma unroll
    for (int rs = 0; rs < 4; ++rs) {
        const int rt = rs * 16 + col;
        const int sw = (rt & 7) << 3;
#pragma unroll
        for (int kc = 0; kc < 2; ++kc)
            afh[rs][kc] = *(const short8*)&Ah[rt * 64 + ((kc * 32 + kseg * 8) ^ sw)];
    }

    u32 keys[16];
#pragma unroll
    for (int i = 0; i < 16; ++i) keys[i] = 0xFFFFFFFFu;

    const int fragoff = kseg * 128 + col * 8;   // within a 1KB cbT chunk

    // Named double-buffer register sets (NO runtime indexing anywhere).
    short8 bA00, bA01, bA10, bA11, bB00, bB01, bB10, bB11;
    float  cnA0, cnA1, cnB0, cnB1;

#define PREFETCH(S00, S01, S10, S11, C0, C1, TILE) do {                       \
        const int _bb = (TILE) * 128 + bg * 32 + col;                         \
        const int _c16 = ((TILE) * 8 + bg * 2) * 1024 + fragoff;              \
        C0 = cbnC[_bb];  C1 = cbnC[_bb + 16];                                 \
        S00 = *(const short8*)&cbT[_c16];                                     \
        S01 = *(const short8*)&cbT[_c16 + 512];                               \
        S10 = *(const short8*)&cbT[_c16 + 1024];                              \
        S11 = *(const short8*)&cbT[_c16 + 1536];                              \
    } while (0)

#define COMPUTE(S00, S01, S10, S11, C0, C1, TILE) do {                        \
        f32x4 acc[4][2];                                                      \
        _Pragma("unroll")                                                     \
        for (int rs = 0; rs < 4; ++rs) {                                      \
            f32x4 a0 = {0.f, 0.f, 0.f, 0.f}, a1 = {0.f, 0.f, 0.f, 0.f};      \
            a0 = MFMA_BF16(afh[rs][0], S00, a0, 0, 0, 0);                     \
            a0 = MFMA_BF16(afh[rs][1], S01, a0, 0, 0, 0);                     \
            a1 = MFMA_BF16(afh[rs][0], S10, a1, 0, 0, 0);                     \
            a1 = MFMA_BF16(afh[rs][1], S11, a1, 0, 0, 0);                     \
            acc[rs][0] = a0; acc[rs][1] = a1;                                 \
        }                                                                     \
        const u32 bin0 = (u32)((TILE) * 128 + bg * 32 + col);                 \
        const u32 bin1 = bin0 + 16;                                           \
        _Pragma("unroll")                                                     \
        for (int rs = 0; rs < 4; ++rs) {                                      \
            _Pragma("unroll")                                                 \
            for (int jj = 0; jj < 4; ++jj) {                                  \
                float d0 = fmaf(-2.f, acc[rs][0][jj], C0);                    \
                float d1 = fmaf(-2.f, acc[rs][1][jj], C1);                    \
                u32 k0 = (__float_as_uint(d0) & KEYMASK) | bin0;              \
                u32 k1 = (__float_as_uint(d1) & KEYMASK) | bin1;              \
                u32 km = k0 < k1 ? k0 : k1;                                   \
                int li = rs * 4 + jj;                                         \
                keys[li] = km < keys[li] ? km : keys[li];                     \
            }                                                                 \
        }                                                                     \
    } while (0)

    PREFETCH(bA00, bA01, bA10, bA11, cnA0, cnA1, 0);
#pragma unroll
    for (int tp = 0; tp < 8; ++tp) {
        const int t1_ = tp * 2 + 1;
        const int t2_ = (tp * 2 + 2) & 15;     // wraps at end: harmless
        PREFETCH(bB00, bB01, bB10, bB11, cnB0, cnB1, t1_);
        COMPUTE(bA00, bA01, bA10, bA11, cnA0, cnA1, tp * 2);
        PREFETCH(bA00, bA01, bA10, bA11, cnA0, cnA1, t2_);
        COMPUTE(bB00, bB01, bB10, bB11, cnB0, cnB1, t1_);
    }
#undef PREFETCH
#undef COMPUTE

    // ---- issue epilogue x-read now (hides HBM latency under reduction) ----
    const size_t ob = (size_t)r0 * 64 + (size_t)tid * 16;
    float4 xv0 = *(const float4*)(x + ob);
    float4 xv1 = *(const float4*)(x + ob + 4);
    float4 xv2 = *(const float4*)(x + ob + 8);
    float4 xv3 = *(const float4*)(x + ob + 12);

    // ---- reduce across 16 col-lanes (u32 min = value then lowest bin) ----
#pragma unroll
    for (int m = 1; m <= 8; m <<= 1) {
#pragma unroll
        for (int i = 0; i < 16; ++i) {
            u32 ok = (u32)__shfl_xor((int)keys[i], m, 64);
            keys[i] = ok < keys[i] ? ok : keys[i];
        }
    }
    if (col == 0) {
#pragma unroll
        for (int rs = 0; rs < 4; ++rs)
#pragma unroll
            for (int jj = 0; jj < 4; ++jj)
                kq_s[bg][rs * 16 + kseg * 4 + jj] = keys[rs * 4 + jj];
    }
    __syncthreads();

    // ---- cross-wave merge + fit partial (wave 0) ----
    if (tid < 64) {
        u32 k0 = kq_s[0][tid], k1 = kq_s[1][tid];
        u32 k2 = kq_s[2][tid], k3 = kq_s[3][tid];
        u32 ka = k0 < k1 ? k0 : k1;
        u32 kb2 = k2 < k3 ? k2 : k3;
        u32 km = ka < kb2 ? ka : kb2;
        bi_m[tid] = (int)(km & 0x7FFu);
        float d = __uint_as_float(km & KEYMASK) - DBIAS;
        float fv = sqrtf(fmaxf(xnorm_s[tid] + d, 0.f));
#pragma unroll
        for (int m = 32; m >= 1; m >>= 1) fv += __shfl_xor(fv, m, 64);
        if (tid == 0) fit_part[blockIdx.x] = fv;
    }
    __syncthreads();

    // ---- fused epilogue: raw-view gather + STE write + loss partial ----
    const int rl = tid >> 2;                 // local row 0..63
    const int id = bi_m[rl];
    const float* qrow = cb + (size_t)id * 64 + (tid & 3) * 16;
    float4 q0 = *(const float4*)(qrow);
    float4 q1 = *(const float4*)(qrow + 4);
    float4 q2 = *(const float4*)(qrow + 8);
    float4 q3 = *(const float4*)(qrow + 12);
    float ls = 0.f;
#define STE(QV, XV, OFF) do {                                                 \
        float4 qo;                                                            \
        qo.x = XV.x + (QV.x - XV.x); qo.y = XV.y + (QV.y - XV.y);             \
        qo.z = XV.z + (QV.z - XV.z); qo.w = XV.w + (QV.w - XV.w);             \
        *(float4*)(out + ob + OFF) = qo;                                      \
        float dx = QV.x - XV.x, dy = QV.y - XV.y;                             \
        float dz = QV.z - XV.z, dw = QV.w - XV.w;                             \
        ls += dx * dx + dy * dy + dz * dz + dw * dw;                          \
    } while (0)
    STE(q0, xv0, 0); STE(q1, xv1, 4); STE(q2, xv2, 8); STE(q3, xv3, 12);
#undef STE
#pragma unroll
    for (int m = 32; m >= 1; m >>= 1) ls += __shfl_xor(ls, m, 64);
    if (lane == 0) red_l[bg] = ls;
    __syncthreads();
    if (tid == 0)
        loss_part[blockIdx.x] = red_l[0] + red_l[1] + red_l[2] + red_l[3];
}

// ---------------------------------------------------------------------------
// Final deterministic reduction -> loss, fit scalars
// ---------------------------------------------------------------------------
__global__ __launch_bounds__(256) void final_k(
    const float* __restrict__ loss_part, const float* __restrict__ fit_part,
    float* __restrict__ out) {
    int tid = threadIdx.x;
    float s = loss_part[tid] + loss_part[tid + 256];
    float f = fit_part[tid] + fit_part[tid + 256];
#pragma unroll
    for (int m = 32; m >= 1; m >>= 1) {
        s += __shfl_xor(s, m, 64);
        f += __shfl_xor(f, m, 64);
    }
    __shared__ float ss[4], ff[4];
    if ((tid & 63) == 0) { ss[tid >> 6] = s; ff[tid >> 6] = f; }
    __syncthreads();
    if (tid == 0) {
        float loss_sum = ss[0] + ss[1] + ss[2] + ss[3];
        float fit_sum  = ff[0] + ff[1] + ff[2] + ff[3];
        // loss = codebook_loss + 0.25*commit_loss = 1.25 * mean((q-x)^2)
        out[NELEM]     = 1.25f * loss_sum / (float)NELEM;
        out[NELEM + 1] = fit_sum / (float)NROWS;
    }
}

// ---------------------------------------------------------------------------
extern "C" void kernel_launch(void* const* d_in, const int* in_sizes, int n_in,
                              void* d_out, int out_size, void* d_ws, size_t ws_size,
                              hipStream_t stream) {
    const float* x  = (const float*)d_in[0];   // (16,64,2048) fp32
    const float* cb = (const float*)d_in[1];   // (2048,64) fp32
    float* out = (float*)d_out;                // [2097152 quantized][loss][fit]

    char* ws = (char*)d_ws;
    float* cbnC      = (float*)(ws);            // 8 KB
    u16*   cbT       = (u16*)  (ws + 8192);     // 256 KB
    float* loss_part = (float*)(ws + 270336);   // 2 KB (512 f)
    float* fit_part  = (float*)(ws + 272384);   // 2 KB (512 f)

    cbprep_k<<<8,   256, 0, stream>>>(cb, cbT, cbnC);
    vq_main_k<<<512, 256, 0, stream>>>(x, cbT, cbnC, cb, out, loss_part, fit_part);
    final_k <<<1,   256, 0, stream>>>(loss_part, fit_part, out);
}